// Round 1
// baseline (466.371 us; speedup 1.0000x reference)
//
#include <hip/hip_runtime.h>
#include <cstdint>

// Fused ConvTranspose2d(stride1,crop) + tanh-GELU + per-pixel GroupNorm(8 groups)
// N=32, Cin=64, Cout=128, H=W=128, K=3.
// Implicit GEMM: one block per (n, oh): C[ow=128][oc=128] = A[ow][k=576] * B[k][oc],
// k = (kh*3+kw)*64 + ic, A[ow][k] = x[n, ic, oh-kh, ow-kw] (zero-padded low side).
// bf16 MFMA 16x16x32, fp32 accumulate. GroupNorm group = 16 oc = one MFMA n-tile.

#define NG 8
#define EPS 1e-5f

typedef __attribute__((ext_vector_type(8))) short bf16x8;
typedef __attribute__((ext_vector_type(4))) float f32x4;
typedef __attribute__((ext_vector_type(4))) unsigned int u32x4;

// LDS layout (bytes):
//  GEMM phase : xs  [3 rows][130 wpos][72 ic-padded] bf16   = 56160  @0
//               Bs  double buffer 2 x [128 oc][32 k] bf16   = 16384  @56320
//  Epilogue   : tile[128 oc][132 ow-padded] f32             = 67584  @0
//               mean[8][128], rstd[8][128] f32              =  8192  @67584
#define XS_W 130
#define XS_C 72     // ic stride padded 64->72 (144B, 16B-aligned, even bank spread)
#define BS_OFF 56320
#define TILE_STRIDE 132
#define STAT_OFF (128*TILE_STRIDE*4)          // 67584
#define SMEM_BYTES (STAT_OFF + 2*NG*128*4)    // 75776 (gemm phase needs 72704)

__device__ inline unsigned short f2bf(float f) {   // RTNE fp32->bf16
  unsigned int u = __float_as_uint(f);
  return (unsigned short)((u + 0x7fffu + ((u >> 16) & 1u)) >> 16);
}

__device__ inline float gelu_f(float y) {
  // 0.5*y*(1+tanh(0.7978845608*(y+0.044715*y^3))); tanh(u)=1-2/(exp(2u)+1)
  float u = 0.7978845608f * (y + 0.044715f * y * y * y);
  float e = __expf(2.0f * u);
  float t = 1.0f - 2.0f * __builtin_amdgcn_rcpf(e + 1.0f);
  return 0.5f * y * (1.0f + t);
}

__device__ inline void ldg_lds16(const void* g, void* l) {
  __builtin_amdgcn_global_load_lds(
      (const __attribute__((address_space(1))) void*)g,
      (__attribute__((address_space(3))) void*)l, 16, 0, 0);
}

// Pre-block weights: BT[kk=18][oc=128][k31=32] bf16, global k = kk*32+k31 = tap*64+ic
__global__ void prep_w(const float* __restrict__ w, unsigned short* __restrict__ BT) {
  int idx = blockIdx.x * 256 + threadIdx.x;   // 73728 total
  int k31 = idx & 31;
  int oc  = (idx >> 5) & 127;
  int kk  = idx >> 12;
  int k   = kk * 32 + k31;
  int t   = k >> 6;          // tap = kh*3+kw
  int ic  = k & 63;
  BT[idx] = f2bf(w[(ic * 128 + oc) * 9 + t]);
}

__global__ __launch_bounds__(256, 2)
void conv_gelu_gn(const float* __restrict__ x,
                  const unsigned short* __restrict__ BT,
                  const float* __restrict__ bias,
                  const float* __restrict__ gnw,
                  const float* __restrict__ gnb,
                  float* __restrict__ out) {
  __shared__ __align__(16) unsigned char smem[SMEM_BYTES];
  unsigned short* xs   = (unsigned short*)smem;
  unsigned short* Bs   = (unsigned short*)(smem + BS_OFF);
  float*          tile = (float*)smem;
  float*          meanA = (float*)(smem + STAT_OFF);
  float*          rstdA = meanA + NG * 128;

  const int tid  = threadIdx.x;
  const int oh   = blockIdx.x, n = blockIdx.y;
  const int lane = tid & 63, wave = tid >> 6;
  const int wy   = wave >> 1, wx = wave & 1;   // wave tile: [wy*64 ow][wx*64 oc]
  const int cl   = lane & 15, q = lane >> 4;

  // ---- stage A: x rows oh-2..oh -> xs[r][wpos][ic] bf16, wpos=w+2, wpos<2 = zero pad
  {
    int w_  = tid & 127;
    int icq = tid >> 7;                 // wave-uniform
    #pragma unroll
    for (int rep = 0; rep < 12; ++rep) {
      int slot = rep * 2 + icq;         // 0..23 = (r 0..2) x (ic8 0..7)
      int r = slot >> 3;
      int ic0 = (slot & 7) * 8;
      int h = oh - 2 + r;
      u32x4 pk;
      if (h >= 0) {
        const float* src = x + (((n * 64 + ic0) * 128 + h) * 128) + w_;
        float v0 = src[0],         v1 = src[16384],     v2 = src[2 * 16384], v3 = src[3 * 16384];
        float v4 = src[4 * 16384], v5 = src[5 * 16384], v6 = src[6 * 16384], v7 = src[7 * 16384];
        pk.x = (unsigned)f2bf(v0) | ((unsigned)f2bf(v1) << 16);
        pk.y = (unsigned)f2bf(v2) | ((unsigned)f2bf(v3) << 16);
        pk.z = (unsigned)f2bf(v4) | ((unsigned)f2bf(v5) << 16);
        pk.w = (unsigned)f2bf(v6) | ((unsigned)f2bf(v7) << 16);
      } else {
        pk.x = pk.y = pk.z = pk.w = 0u;
      }
      *(u32x4*)(xs + (r * XS_W + 2 + w_) * XS_C + ic0) = pk;
      if (w_ < 2) {                     // left zero pad (wpos 0,1)
        u32x4 z; z.x = z.y = z.z = z.w = 0u;
        *(u32x4*)(xs + (r * XS_W + w_) * XS_C + ic0) = z;
      }
    }
  }

  // ---- B double-buffered prefetch via global_load_lds (16B/lane)
  auto prefetchB = [&](int kk, int buf) {
    const unsigned short* g = BT + kk * 4096 + tid * 8;
    unsigned short* l = Bs + buf * 4096 + tid * 8;
    ldg_lds16(g, l);
    ldg_lds16(g + 2048, l + 2048);
  };

  f32x4 acc[4][4] = {};
  prefetchB(0, 0);
  __syncthreads();

  const int icq8 = q * 8;
  const int boffBase = (wx * 64 + cl) * 32 + icq8;

  for (int kk = 0; kk < 18; ++kk) {
    if (kk < 17) prefetchB(kk + 1, (kk + 1) & 1);
    int t  = kk >> 1;
    int kh = t / 3, kw = t - kh * 3;
    int icb = (kk & 1) * 32;
    int rowb = (2 - kh) * XS_W + wy * 64 + cl + 2 - kw;   // wpos for m-tile 0
    const unsigned short* ax = xs + rowb * XS_C + icb + icq8;
    bf16x8 a0 = *(const bf16x8*)(ax);
    bf16x8 a1 = *(const bf16x8*)(ax + 16 * XS_C);
    bf16x8 a2 = *(const bf16x8*)(ax + 32 * XS_C);
    bf16x8 a3 = *(const bf16x8*)(ax + 48 * XS_C);
    const unsigned short* bx = Bs + (kk & 1) * 4096 + boffBase;
    bf16x8 b0 = *(const bf16x8*)(bx);
    bf16x8 b1 = *(const bf16x8*)(bx + 16 * 32);
    bf16x8 b2 = *(const bf16x8*)(bx + 32 * 32);
    bf16x8 b3 = *(const bf16x8*)(bx + 48 * 32);
    acc[0][0] = __builtin_amdgcn_mfma_f32_16x16x32_bf16(a0, b0, acc[0][0], 0, 0, 0);
    acc[0][1] = __builtin_amdgcn_mfma_f32_16x16x32_bf16(a0, b1, acc[0][1], 0, 0, 0);
    acc[0][2] = __builtin_amdgcn_mfma_f32_16x16x32_bf16(a0, b2, acc[0][2], 0, 0, 0);
    acc[0][3] = __builtin_amdgcn_mfma_f32_16x16x32_bf16(a0, b3, acc[0][3], 0, 0, 0);
    acc[1][0] = __builtin_amdgcn_mfma_f32_16x16x32_bf16(a1, b0, acc[1][0], 0, 0, 0);
    acc[1][1] = __builtin_amdgcn_mfma_f32_16x16x32_bf16(a1, b1, acc[1][1], 0, 0, 0);
    acc[1][2] = __builtin_amdgcn_mfma_f32_16x16x32_bf16(a1, b2, acc[1][2], 0, 0, 0);
    acc[1][3] = __builtin_amdgcn_mfma_f32_16x16x32_bf16(a1, b3, acc[1][3], 0, 0, 0);
    acc[2][0] = __builtin_amdgcn_mfma_f32_16x16x32_bf16(a2, b0, acc[2][0], 0, 0, 0);
    acc[2][1] = __builtin_amdgcn_mfma_f32_16x16x32_bf16(a2, b1, acc[2][1], 0, 0, 0);
    acc[2][2] = __builtin_amdgcn_mfma_f32_16x16x32_bf16(a2, b2, acc[2][2], 0, 0, 0);
    acc[2][3] = __builtin_amdgcn_mfma_f32_16x16x32_bf16(a2, b3, acc[2][3], 0, 0, 0);
    acc[3][0] = __builtin_amdgcn_mfma_f32_16x16x32_bf16(a3, b0, acc[3][0], 0, 0, 0);
    acc[3][1] = __builtin_amdgcn_mfma_f32_16x16x32_bf16(a3, b1, acc[3][1], 0, 0, 0);
    acc[3][2] = __builtin_amdgcn_mfma_f32_16x16x32_bf16(a3, b2, acc[3][2], 0, 0, 0);
    acc[3][3] = __builtin_amdgcn_mfma_f32_16x16x32_bf16(a3, b3, acc[3][3], 0, 0, 0);
    __syncthreads();   // drains prefetch vmcnt + guards buffer swap (m97 structure)
  }

  // ---- epilogue: bias + GELU in regs, transpose via LDS tile[oc][ow]
  float bj[4];
  #pragma unroll
  for (int j = 0; j < 4; ++j) bj[j] = bias[wx * 64 + j * 16 + cl];

  #pragma unroll
  for (int i = 0; i < 4; ++i) {
    int owb = wy * 64 + i * 16 + q * 4;     // D row = ow = q*4+reg
    #pragma unroll
    for (int j = 0; j < 4; ++j) {
      int oc = wx * 64 + j * 16 + cl;       // D col = oc = lane&15
      f32x4 v = acc[i][j];
      f32x4 g4;
      #pragma unroll
      for (int r = 0; r < 4; ++r) g4[r] = gelu_f(v[r] + bj[j]);
      *(f32x4*)(tile + oc * TILE_STRIDE + owb) = g4;
    }
  }
  __syncthreads();

  // ---- per-pixel group stats: (g, ow) over 16 oc
  for (int s = tid; s < NG * 128; s += 256) {
    int g = s >> 7, ow = s & 127;
    const float* p = tile + (g * 16) * TILE_STRIDE + ow;
    float sum = 0.f, s2 = 0.f;
    #pragma unroll
    for (int k = 0; k < 16; ++k) {
      float v = p[k * TILE_STRIDE];
      sum += v; s2 += v * v;
    }
    float mean = sum * (1.f / 16.f);
    float var  = s2 * (1.f / 16.f) - mean * mean;
    meanA[s] = mean;
    rstdA[s] = __builtin_amdgcn_rsqf(var + EPS);
  }
  __syncthreads();

  // ---- normalize + affine + coalesced store
  #pragma unroll 4
  for (int it = 0; it < 16; ++it) {
    int idx = it * 256 + tid;
    int ow4 = (idx & 31) * 4;
    int oc  = idx >> 5;
    int g   = oc >> 4;
    float gw = gnw[oc], gb = gnb[oc];
    f32x4 v  = *(const f32x4*)(tile + oc * TILE_STRIDE + ow4);
    f32x4 m4 = *(const f32x4*)(meanA + g * 128 + ow4);
    f32x4 r4 = *(const f32x4*)(rstdA + g * 128 + ow4);
    f32x4 o;
    #pragma unroll
    for (int r = 0; r < 4; ++r) o[r] = (v[r] - m4[r]) * r4[r] * gw + gb;
    *(f32x4*)(out + ((n * 128 + oc) * 128 + oh) * 128 + ow4) = o;
  }
}

extern "C" void kernel_launch(void* const* d_in, const int* in_sizes, int n_in,
                              void* d_out, int out_size, void* d_ws, size_t ws_size,
                              hipStream_t stream) {
  const float* x   = (const float*)d_in[0];
  const float* w   = (const float*)d_in[1];
  const float* b   = (const float*)d_in[2];
  const float* gnw = (const float*)d_in[3];
  const float* gnb = (const float*)d_in[4];
  float* out = (float*)d_out;
  unsigned short* BT = (unsigned short*)d_ws;   // 18*128*32 bf16 = 147456 B

  prep_w<<<288, 256, 0, stream>>>(w, BT);
  conv_gelu_gn<<<dim3(128, 32), 256, 0, stream>>>(x, BT, b, gnw, gnb, out);
}